// Round 1
// baseline (240.094 us; speedup 1.0000x reference)
//
#include <hip/hip_runtime.h>

// Sparsemax along last axis, D=32, rows = 1024*4096.
// Michelot projection-onto-simplex: tau = (sum_{x>tau} x - 1)/count, iterate
// to fixed point. tau is monotone non-decreasing => recompute support from all
// 32 elements each iteration (no mask state), count >= 1 always.
#define D 32

__global__ __launch_bounds__(256) void sparsemax_kernel(const float* __restrict__ in,
                                                        float* __restrict__ out,
                                                        int nrows) {
    int row = blockIdx.x * blockDim.x + threadIdx.x;
    if (row >= nrows) return;

    const float4* in4 = reinterpret_cast<const float4*>(in) + (size_t)row * (D / 4);
    float x[D];
#pragma unroll
    for (int i = 0; i < D / 4; ++i) {
        float4 v = in4[i];
        x[4 * i + 0] = v.x;
        x[4 * i + 1] = v.y;
        x[4 * i + 2] = v.z;
        x[4 * i + 3] = v.w;
    }

    // Iteration 0: full-set estimate.
    float s = 0.0f;
#pragma unroll
    for (int j = 0; j < D; ++j) s += x[j];
    float tau = (s - 1.0f) * (1.0f / (float)D);
    int c_prev = D;

    // Michelot fixed-point loop (wave-uniform trip count via __all).
#pragma unroll 1
    for (int it = 0; it < D; ++it) {
        float s2 = 0.0f;
        int c = 0;
#pragma unroll
        for (int j = 0; j < D; ++j) {
            bool a = x[j] > tau;
            s2 += a ? x[j] : 0.0f;
            c += a ? 1 : 0;
        }
        // If c == c_prev the support set is unchanged (sets are nested +
        // equal cardinality), so s2 and the new tau are bitwise-identical to
        // the previous ones -> unconditional update is safe and idempotent.
        tau = (s2 - 1.0f) / (float)c;
        bool done = (c == c_prev);
        c_prev = c;
        if (__all(done)) break;
    }

    float4* out4 = reinterpret_cast<float4*>(out) + (size_t)row * (D / 4);
#pragma unroll
    for (int i = 0; i < D / 4; ++i) {
        float4 v;
        v.x = fmaxf(x[4 * i + 0] - tau, 0.0f);
        v.y = fmaxf(x[4 * i + 1] - tau, 0.0f);
        v.z = fmaxf(x[4 * i + 2] - tau, 0.0f);
        v.w = fmaxf(x[4 * i + 3] - tau, 0.0f);
        out4[i] = v;
    }
}

extern "C" void kernel_launch(void* const* d_in, const int* in_sizes, int n_in,
                              void* d_out, int out_size, void* d_ws, size_t ws_size,
                              hipStream_t stream) {
    const float* in = (const float*)d_in[0];
    float* out = (float*)d_out;
    int nrows = in_sizes[0] / D;  // 4,194,304
    int block = 256;
    int grid = (nrows + block - 1) / block;
    sparsemax_kernel<<<grid, block, 0, stream>>>(in, out, nrows);
}

// Round 2
// 188.489 us; speedup vs baseline: 1.2738x; 1.2738x over previous
//
#include <hip/hip_runtime.h>

// Sparsemax along last axis, D=32, rows = 1024*4096 = 4,194,304.
//
// Layout: one row per 8-lane group; each lane holds one float4 (4 elements).
// Global flat float4 index == global thread id -> perfectly coalesced 1-KiB
// wave loads/stores (16 cache lines per VMEM instr instead of 64 for the
// previous row-per-thread layout).
//
// Michelot projection-onto-simplex: tau <- (sum_{x>tau} x - 1)/count until
// count stops changing. tau monotone non-decreasing => recompute support from
// all elements each iteration; count >= 1 always. Sum/count reduced over the
// 8-lane group with DPP adds (VALU pipe, no LDS):
//   quad_perm[1,0,3,2] (xor1) -> quad_perm[2,3,0,1] (xor2) -> row_half_mirror.

#define D 32

template <int CTRL>
__device__ __forceinline__ float dpp_mov(float v) {
    return __int_as_float(
        __builtin_amdgcn_update_dpp(0, __float_as_int(v), CTRL, 0xF, 0xF, true));
}

// Sum over each aligned 8-lane group; result valid in all 8 lanes.
__device__ __forceinline__ float reduce8(float v) {
    v += dpp_mov<0xB1>(v);   // quad_perm [1,0,3,2] : pair sum (xor 1)
    v += dpp_mov<0x4E>(v);   // quad_perm [2,3,0,1] : quad sum (xor 2)
    v += dpp_mov<0x141>(v);  // row_half_mirror     : combine the two quads
    return v;
}

__global__ __launch_bounds__(256) void sparsemax_kernel(const float4* __restrict__ in4,
                                                        float4* __restrict__ out4) {
    int t = blockIdx.x * blockDim.x + threadIdx.x;  // == flat float4 index

    float4 v = in4[t];
    float e0 = v.x, e1 = v.y, e2 = v.z, e3 = v.w;

    // Iteration 0: full-set estimate.
    float S = reduce8(e0 + e1 + e2 + e3);
    float tau = (S - 1.0f) * (1.0f / 32.0f);
    float Cprev = 32.0f;

    // Michelot fixed-point loop (wave-uniform trip count via __all; converged
    // groups keep recomputing the identical tau, which is idempotent).
#pragma unroll 1
    for (int it = 0; it < D; ++it) {
        float s = 0.0f, c = 0.0f;
        s += (e0 > tau) ? e0 : 0.0f;  c += (e0 > tau) ? 1.0f : 0.0f;
        s += (e1 > tau) ? e1 : 0.0f;  c += (e1 > tau) ? 1.0f : 0.0f;
        s += (e2 > tau) ? e2 : 0.0f;  c += (e2 > tau) ? 1.0f : 0.0f;
        s += (e3 > tau) ? e3 : 0.0f;  c += (e3 > tau) ? 1.0f : 0.0f;

        float S2 = reduce8(s);
        float C  = reduce8(c);        // exact small integer in fp32
        tau = (S2 - 1.0f) / C;

        bool done = (C == Cprev);     // support unchanged -> tau fixed point
        Cprev = C;
        if (__all(done)) break;
    }

    float4 o;
    o.x = fmaxf(e0 - tau, 0.0f);
    o.y = fmaxf(e1 - tau, 0.0f);
    o.z = fmaxf(e2 - tau, 0.0f);
    o.w = fmaxf(e3 - tau, 0.0f);
    out4[t] = o;
}

extern "C" void kernel_launch(void* const* d_in, const int* in_sizes, int n_in,
                              void* d_out, int out_size, void* d_ws, size_t ws_size,
                              hipStream_t stream) {
    const float4* in4 = (const float4*)d_in[0];
    float4* out4 = (float4*)d_out;
    int n4 = in_sizes[0] / 4;            // 33,554,432 float4s == threads
    int block = 256;
    int grid = n4 / block;               // exact: 131072 blocks, no tail
    sparsemax_kernel<<<grid, block, 0, stream>>>(in4, out4);
}